// Round 5
// baseline (3304.264 us; speedup 1.0000x reference)
//
#include <hip/hip_runtime.h>
#include <cstdint>
#include <cstddef>

#define HID 128
#define BSHIFT 7            // 128 nodes per bucket -> nbuck = 782 for N=100000
#define NSB 256             // scatter blocks (pass1/pass2 chunking)

// ---------------- small transpose (weights, once per launch) ----------------
__global__ void transpose_kernel(const float* __restrict__ src, float* __restrict__ dst,
                                 int R, int C) {
  int i = blockIdx.x * blockDim.x + threadIdx.x;
  if (i < R * C) {
    int r = i / C, c = i - r * C;
    dst[c * R + r] = src[i];
  }
}

// ======== deterministic two-pass bucket scatter (NO global atomics) ========
// pass 1: per-block LDS histogram of edge buckets -> countsT[bucket][block]
__global__ __launch_bounds__(256)
void ecount_kernel(const int* __restrict__ row, int* __restrict__ countsT,
                   int E, int nbuck) {
  __shared__ int lh[1024];
  int b = blockIdx.x;
  for (int i = threadIdx.x; i < nbuck; i += 256) lh[i] = 0;
  __syncthreads();
  int per = (E + NSB - 1) / NSB;
  int s = b * per, e = min(s + per, E);
  for (int i = s + (int)threadIdx.x; i < e; i += 256)
    atomicAdd(&lh[row[i] >> BSHIFT], 1);   // LDS atomic, ~8 deep avg
  __syncthreads();
  for (int i = threadIdx.x; i < nbuck; i += 256) countsT[i * NSB + b] = lh[i];
}

// per-bucket exclusive scan over the NSB block counts (in place) + bucket total
__global__ __launch_bounds__(NSB)
void bprefix_kernel(int* __restrict__ countsT, int* __restrict__ btotal, int nbuck) {
  __shared__ int sd[NSB];
  int bk = blockIdx.x;
  int t = threadIdx.x;
  int v = countsT[bk * NSB + t];
  sd[t] = v;
  __syncthreads();
  for (int off = 1; off < NSB; off <<= 1) {
    int u = (t >= off) ? sd[t - off] : 0;
    __syncthreads();
    sd[t] += u;
    __syncthreads();
  }
  countsT[bk * NSB + t] = sd[t] - v;       // exclusive within bucket
  if (t == NSB - 1) btotal[bk] = sd[t];
}

// exclusive scan of bucket totals -> bstart[0..nbuck], bstart[nbuck]=E
__global__ __launch_bounds__(1024)
void bstart_kernel(const int* __restrict__ btotal, int* __restrict__ bstart, int nbuck) {
  __shared__ int sd[1024];
  int t = threadIdx.x;
  int v = (t < nbuck) ? btotal[t] : 0;
  sd[t] = v;
  __syncthreads();
  for (int off = 1; off < 1024; off <<= 1) {
    int u = (t >= off) ? sd[t - off] : 0;
    __syncthreads();
    sd[t] += u;
    __syncthreads();
  }
  if (t < nbuck) bstart[t] = sd[t] - v;
  if (t == nbuck - 1) bstart[nbuck] = sd[t];
}

// pass 2: write (row,col) pairs to bucket-grouped ebuf at precomputed offsets.
// Only LDS atomics (local rank); global writes are dense (~64B/bucket/block).
__global__ __launch_bounds__(256)
void escatter_kernel(const int* __restrict__ row, const int* __restrict__ col,
                     const int* __restrict__ countsT, const int* __restrict__ bstart,
                     int2* __restrict__ ebuf, int E, int nbuck) {
  __shared__ int lcur[1024];
  int b = blockIdx.x;
  for (int i = threadIdx.x; i < nbuck; i += 256)
    lcur[i] = bstart[i] + countsT[i * NSB + b];
  __syncthreads();
  int per = (E + NSB - 1) / NSB;
  int s = b * per, e = min(s + per, E);
  for (int i = s + (int)threadIdx.x; i < e; i += 256) {
    int r = row[i], c = col[i];
    int pos = atomicAdd(&lcur[r >> BSHIFT], 1);
    ebuf[pos] = make_int2(r, c);
  }
}

// ======== bucket aggregation: diff[r][d] = sum_{e: row=r} |h[r][d]-h[col][d]| ====
// One block per bucket (128 nodes). acc[128][128] = 64KB LDS (2 blocks/CU,
// 16 waves). Edges read dense from ebuf; h[col] gathered with 4-edge unroll;
// LDS float atomics (lanes hit distinct banks, 2-way aliasing = free).
__global__ __launch_bounds__(512)
void bagg_kernel(const float* __restrict__ h, const int2* __restrict__ ebuf,
                 const int* __restrict__ bstart, float* __restrict__ diff,
                 int N, int nbuck) {
  __shared__ float acc[128][HID];   // 65536 B
  int tid = threadIdx.x;
  float4 z4 = make_float4(0.f, 0.f, 0.f, 0.f);
  for (int i = tid; i < 128 * (HID / 4); i += 512) ((float4*)acc)[i] = z4;
  __syncthreads();
  int bk = blockIdx.x;
  int s = bstart[bk], e = bstart[bk + 1];
  int cnt = e - s;
  int lane = tid & 63, wv = tid >> 6;       // 8 waves
  int chunk = (cnt + 7) >> 3;
  int cs = s + wv * chunk;
  int ce = min(cs + chunk, e);
  int i = cs;
  for (; i + 4 <= ce; i += 4) {
    int2 rc0 = ebuf[i + 0], rc1 = ebuf[i + 1], rc2 = ebuf[i + 2], rc3 = ebuf[i + 3];
    const float* c0 = h + (size_t)rc0.y * HID;
    const float* c1 = h + (size_t)rc1.y * HID;
    const float* c2 = h + (size_t)rc2.y * HID;
    const float* c3 = h + (size_t)rc3.y * HID;
    float x00 = c0[lane], x01 = c0[lane + 64];
    float x10 = c1[lane], x11 = c1[lane + 64];
    float x20 = c2[lane], x21 = c2[lane + 64];
    float x30 = c3[lane], x31 = c3[lane + 64];
    const float* r0 = h + (size_t)rc0.x * HID;
    const float* r1 = h + (size_t)rc1.x * HID;
    const float* r2 = h + (size_t)rc2.x * HID;
    const float* r3 = h + (size_t)rc3.x * HID;
    float y00 = r0[lane], y01 = r0[lane + 64];
    float y10 = r1[lane], y11 = r1[lane + 64];
    float y20 = r2[lane], y21 = r2[lane + 64];
    float y30 = r3[lane], y31 = r3[lane + 64];
    atomicAdd(&acc[rc0.x & 127][lane],      fabsf(y00 - x00));
    atomicAdd(&acc[rc0.x & 127][lane + 64], fabsf(y01 - x01));
    atomicAdd(&acc[rc1.x & 127][lane],      fabsf(y10 - x10));
    atomicAdd(&acc[rc1.x & 127][lane + 64], fabsf(y11 - x11));
    atomicAdd(&acc[rc2.x & 127][lane],      fabsf(y20 - x20));
    atomicAdd(&acc[rc2.x & 127][lane + 64], fabsf(y21 - x21));
    atomicAdd(&acc[rc3.x & 127][lane],      fabsf(y30 - x30));
    atomicAdd(&acc[rc3.x & 127][lane + 64], fabsf(y31 - x31));
  }
  for (; i < ce; ++i) {
    int2 rc = ebuf[i];
    const float* c0 = h + (size_t)rc.y * HID;
    const float* r0 = h + (size_t)rc.x * HID;
    atomicAdd(&acc[rc.x & 127][lane],      fabsf(r0[lane] - c0[lane]));
    atomicAdd(&acc[rc.x & 127][lane + 64], fabsf(r0[lane + 64] - c0[lane + 64]));
  }
  __syncthreads();
  int base = bk << BSHIFT;
  for (int f = tid; f < 128 * (HID / 4); f += 512) {
    int r = f >> 5, c4 = (f & 31) << 2;
    int node = base + r;
    if (node < N)
      *(float4*)(diff + (size_t)node * HID + c4) = *(float4*)&acc[r][c4];
  }
}

// ---------------- tiled fp32 GEMM: C = relu([A1|A2] @ BT + bias), opt tau ----
// Register-prefetch double-buffer (chunk k+1 loads overlap compute of chunk k).
template<bool TAU>
__global__ __launch_bounds__(256)
void gemm_kernel(const float* __restrict__ A1, const float* __restrict__ A2,
                 const float* __restrict__ BT, const float* __restrict__ bias,
                 float* __restrict__ C, int M, int nchunks,
                 const float* __restrict__ Wt, const float* __restrict__ bt,
                 float* __restrict__ tau_out) {
  __shared__ float As[32][132];   // [k][i], padded leading dim
  __shared__ float Bs[32][128];   // [k][c]
  __shared__ float taured[128];
  int tid = threadIdx.x;
  int tx = tid & 15;   // col group: cols tx + 16*u
  int ty = tid >> 4;   // row group: rows ty*8 + r
  int i0 = blockIdx.x * 128;
  float acc[8][8] = {};
  float4 pa[4], pb[4];

  auto load_chunk = [&](int kc) {
    const float* A = (kc < 4) ? A1 : A2;
    int ksrc = (kc & 3) * 32;
    int kglob = kc * 32;
    #pragma unroll
    for (int q = 0; q < 4; ++q) {
      int f = q * 256 + tid;
      int i = f >> 3;
      int kq = (f & 7) << 2;
      int ig = i0 + i; if (ig >= M) ig = M - 1;
      pa[q] = *(const float4*)(A + (size_t)ig * HID + ksrc + kq);
      int k = f >> 5; int c4 = (f & 31) << 2;
      pb[q] = *(const float4*)(BT + (size_t)(kglob + k) * HID + c4);
    }
  };
  auto stage = [&]() {
    #pragma unroll
    for (int q = 0; q < 4; ++q) {
      int f = q * 256 + tid;
      int i = f >> 3;
      int kq = (f & 7) << 2;
      As[kq + 0][i] = pa[q].x; As[kq + 1][i] = pa[q].y;
      As[kq + 2][i] = pa[q].z; As[kq + 3][i] = pa[q].w;
      int k = f >> 5; int c4 = (f & 31) << 2;
      *(float4*)&Bs[k][c4] = pb[q];
    }
  };

  load_chunk(0);
  for (int kc = 0; kc < nchunks; ++kc) {
    __syncthreads();
    stage();
    __syncthreads();
    if (kc + 1 < nchunks) load_chunk(kc + 1);
    #pragma unroll
    for (int k = 0; k < 32; ++k) {
      float a[8], b[8];
      const float4* ap = (const float4*)&As[k][ty * 8];
      float4 a0 = ap[0], a1 = ap[1];
      a[0]=a0.x; a[1]=a0.y; a[2]=a0.z; a[3]=a0.w;
      a[4]=a1.x; a[5]=a1.y; a[6]=a1.z; a[7]=a1.w;
      #pragma unroll
      for (int u = 0; u < 8; ++u) b[u] = Bs[k][tx + 16 * u];
      #pragma unroll
      for (int r = 0; r < 8; ++r)
        #pragma unroll
        for (int u = 0; u < 8; ++u)
          acc[r][u] = fmaf(a[r], b[u], acc[r][u]);
    }
  }

  float bias_r[8], wt_r[8];
  #pragma unroll
  for (int u = 0; u < 8; ++u) { bias_r[u] = bias[tx + 16 * u]; wt_r[u] = 0.f; }
  if constexpr (TAU) {
    #pragma unroll
    for (int u = 0; u < 8; ++u) wt_r[u] = Wt[tx + 16 * u];
  }
  #pragma unroll
  for (int r = 0; r < 8; ++r) {
    int row = i0 + ty * 8 + r;
    bool ok = row < M;
    float p = 0.f;
    #pragma unroll
    for (int u = 0; u < 8; ++u) {
      float v = fmaxf(acc[r][u] + bias_r[u], 0.f);
      if (ok) C[(size_t)row * HID + tx + 16 * u] = v;
      p = fmaf(v, wt_r[u], p);
    }
    if constexpr (TAU) {
      p += __shfl_down(p, 8);
      p += __shfl_down(p, 4);
      p += __shfl_down(p, 2);
      p += __shfl_down(p, 1);
      if (tx == 0) taured[ty * 8 + r] = p;
    }
  }
  if constexpr (TAU) {
    __syncthreads();
    if (tid < 128) {
      int row = i0 + tid;
      if (row < M) {
        float pre = taured[tid] + bt[0];
        float tau = (pre > 20.f) ? pre : log1pf(expf(pre));
        tau_out[row] = tau;
      }
    }
  }
}

// ---------------- mask + compaction ----------------
// np semantics: floor(1/tau).astype(int32) overflows to INT_MIN for 1/tau >= 2^31
// -> n_updates <= 0 -> NOT masked even though tau < 0.005.
__global__ void compact_kernel(const float* __restrict__ tau, int* __restrict__ list,
                               int* __restrict__ count, int N) {
  for (int i = blockIdx.x * blockDim.x + threadIdx.x; i < N; i += gridDim.x * blockDim.x) {
    float t = tau[i];
    if (t < 0.005f && (1.0f / t) < 2147483648.0f) {
      int p = atomicAdd(count, 1);
      list[p] = i;
    }
  }
}

// ---------------- masked GRU, 16 nodes / block ----------------
__global__ __launch_bounds__(256)
void gru_kernel(const float* __restrict__ diff, float* __restrict__ h,
                const int* __restrict__ list, const int* __restrict__ count,
                const float* __restrict__ WihT, const float* __restrict__ WhhT,
                const float* __restrict__ b_ih, const float* __restrict__ b_hh) {
  int cnt = *count;
  int base = blockIdx.x * 16;
  if (base >= cnt) return;
  __shared__ float dl[16][HID];
  __shared__ float hl[16][HID];
  __shared__ int ids[16];
  int tid = threadIdx.x;
  if (tid < 16) ids[tid] = (base + tid < cnt) ? list[base + tid] : -1;
  __syncthreads();
  #pragma unroll
  for (int q = 0; q < 8; ++q) {
    int f = q * 256 + tid;
    int r = f >> 7, c = f & 127;
    int id = ids[r];
    int src = (id >= 0) ? id : 0;
    dl[r][c] = diff[(size_t)src * HID + c];
    hl[r][c] = h[(size_t)src * HID + c];
  }
  __syncthreads();
  int tx = tid & 127, ty = tid >> 7;
  float air[8] = {}, aiz[8] = {}, ain[8] = {}, ahr[8] = {}, ahz[8] = {}, ahn[8] = {};
  for (int k = 0; k < HID; ++k) {
    float wir = WihT[k * 384 + tx];
    float wiz = WihT[k * 384 + 128 + tx];
    float win = WihT[k * 384 + 256 + tx];
    float whr = WhhT[k * 384 + tx];
    float whz = WhhT[k * 384 + 128 + tx];
    float whn = WhhT[k * 384 + 256 + tx];
    #pragma unroll
    for (int r = 0; r < 8; ++r) {
      float dk = dl[ty * 8 + r][k];
      float hk = hl[ty * 8 + r][k];
      air[r] = fmaf(dk, wir, air[r]);
      aiz[r] = fmaf(dk, wiz, aiz[r]);
      ain[r] = fmaf(dk, win, ain[r]);
      ahr[r] = fmaf(hk, whr, ahr[r]);
      ahz[r] = fmaf(hk, whz, ahz[r]);
      ahn[r] = fmaf(hk, whn, ahn[r]);
    }
  }
  float bir = b_ih[tx], biz = b_ih[128 + tx], bin = b_ih[256 + tx];
  float bhr = b_hh[tx], bhz = b_hh[128 + tx], bhn = b_hh[256 + tx];
  #pragma unroll
  for (int r = 0; r < 8; ++r) {
    int id = ids[ty * 8 + r];
    if (id < 0) continue;
    float rg = 1.f / (1.f + expf(-((air[r] + bir) + (ahr[r] + bhr))));
    float z  = 1.f / (1.f + expf(-((aiz[r] + biz) + (ahz[r] + bhz))));
    float n  = tanhf((ain[r] + bin) + rg * (ahn[r] + bhn));
    float hv = hl[ty * 8 + r][tx];
    h[(size_t)id * HID + tx] = (1.f - z) * n + z * hv;
  }
}

// ---------------- output head: out = h @ Wo^T + bo  (wave per node) ----------
__global__ void out_kernel(const float* __restrict__ h, const float* __restrict__ Wo,
                           const float* __restrict__ bo, float* __restrict__ out, int N) {
  int g = blockIdx.x * blockDim.x + threadIdx.x;
  int node = g >> 6;
  int lane = threadIdx.x & 63;
  if (node >= N) return;
  float h0 = h[(size_t)node * HID + lane];
  float h1 = h[(size_t)node * HID + 64 + lane];
  float s0 = h0 * Wo[lane] + h1 * Wo[64 + lane];
  float s1 = h0 * Wo[128 + lane] + h1 * Wo[192 + lane];
  for (int d = 32; d; d >>= 1) {
    s0 += __shfl_down(s0, d);
    s1 += __shfl_down(s1, d);
  }
  if (lane == 0) {
    out[(size_t)node * 2 + 0] = s0 + bo[0];
    out[(size_t)node * 2 + 1] = s1 + bo[1];
  }
}

extern "C" void kernel_launch(void* const* d_in, const int* in_sizes, int n_in,
                              void* d_out, int out_size, void* d_ws, size_t ws_size,
                              hipStream_t stream) {
  const float* x    = (const float*)d_in[0];
  const int*   ei   = (const int*)d_in[1];
  const float* W_in = (const float*)d_in[2];
  const float* b_in = (const float*)d_in[3];
  const float* Wd   = (const float*)d_in[4];
  const float* bd   = (const float*)d_in[5];
  const float* Wt   = (const float*)d_in[6];
  const float* bt   = (const float*)d_in[7];
  const float* W_ih = (const float*)d_in[8];
  const float* W_hh = (const float*)d_in[9];
  const float* b_ih = (const float*)d_in[10];
  const float* b_hh = (const float*)d_in[11];
  const float* Wo   = (const float*)d_in[12];
  const float* bo   = (const float*)d_in[13];

  const int N = in_sizes[0] / HID;      // 100000
  const int E = in_sizes[1] / 2;        // 1600000
  const int* rowp = ei;
  const int* colp = ei + E;
  const int nbuck = (N + (1 << BSHIFT) - 1) >> BSHIFT;   // 782 (<=1024)

  // workspace carve-up (256B aligned)
  char* p = (char*)d_ws;
  auto alloc = [&](size_t bytes) { void* r = (void*)p; p += (bytes + 255) & ~(size_t)255; return r; };
  float* hA     = (float*)alloc((size_t)N * HID * 4);
  float* hB     = (float*)alloc((size_t)N * HID * 4);
  float* diff   = (float*)alloc((size_t)N * HID * 4);
  float* WinT   = (float*)alloc(128 * 128 * 4);
  float* WdT0   = (float*)alloc(256 * 128 * 4);
  float* WdT1   = (float*)alloc(256 * 128 * 4);
  float* WihT   = (float*)alloc(128 * 384 * 4);
  float* WhhT   = (float*)alloc(128 * 384 * 4);
  float* tau0   = (float*)alloc((size_t)N * 4);
  int*   list   = (int*)alloc((size_t)N * 4);
  int*   count  = (int*)alloc(256);
  int*   countsT= (int*)alloc((size_t)1024 * NSB * 4);
  int*   btotal = (int*)alloc(1024 * 4);
  int*   bstart = (int*)alloc(1028 * 4);
  int2*  ebuf   = (int2*)alloc((size_t)E * 8);

  float* out_ptr = (float*)d_out;            // [N,2] flat
  float* tau_out = (float*)d_out + (size_t)N * 2;  // [N]

  // weight transposes
  transpose_kernel<<<(128 * 128 + 255) / 256, 256, 0, stream>>>(W_in, WinT, 128, 128);
  transpose_kernel<<<(128 * 256 + 255) / 256, 256, 0, stream>>>(Wd, WdT0, 128, 256);
  transpose_kernel<<<(128 * 256 + 255) / 256, 256, 0, stream>>>(Wd + 128 * 256, WdT1, 128, 256);
  transpose_kernel<<<(384 * 128 + 255) / 256, 256, 0, stream>>>(W_ih, WihT, 384, 128);
  transpose_kernel<<<(384 * 128 + 255) / 256, 256, 0, stream>>>(W_hh, WhhT, 384, 128);

  // deterministic bucket-grouped edge buffer (reused by both layers)
  ecount_kernel<<<NSB, 256, 0, stream>>>(rowp, countsT, E, nbuck);
  bprefix_kernel<<<nbuck, NSB, 0, stream>>>(countsT, btotal, nbuck);
  bstart_kernel<<<1, 1024, 0, stream>>>(btotal, bstart, nbuck);
  escatter_kernel<<<NSB, 256, 0, stream>>>(rowp, colp, countsT, bstart, ebuf, E, nbuck);

  const int gemm_blocks = (N + 127) / 128;

  // input layer: hA = relu(x @ Win^T + b_in)
  gemm_kernel<false><<<gemm_blocks, 256, 0, stream>>>(
      x, nullptr, WinT, b_in, hA, N, 4, nullptr, nullptr, nullptr);

  // ---- layer 0 ----
  bagg_kernel<<<nbuck, 512, 0, stream>>>(hA, ebuf, bstart, diff, N, nbuck);
  gemm_kernel<true><<<gemm_blocks, 256, 0, stream>>>(
      hA, diff, WdT0, bd, hB, N, 8, Wt, bt, tau0);
  hipMemsetAsync(count, 0, 4, stream);
  compact_kernel<<<(N + 255) / 256, 256, 0, stream>>>(tau0, list, count, N);
  gru_kernel<<<(N + 15) / 16, 256, 0, stream>>>(diff, hB, list, count, WihT, WhhT, b_ih, b_hh);

  // ---- layer 1 ----
  bagg_kernel<<<nbuck, 512, 0, stream>>>(hB, ebuf, bstart, diff, N, nbuck);
  gemm_kernel<true><<<gemm_blocks, 256, 0, stream>>>(
      hB, diff, WdT1, bd + 128, hA, N, 8, Wt, bt, tau_out);
  hipMemsetAsync(count, 0, 4, stream);
  compact_kernel<<<(N + 255) / 256, 256, 0, stream>>>(tau_out, list, count, N);
  gru_kernel<<<(N + 15) / 16, 256, 0, stream>>>(diff, hA, list, count, WihT, WhhT, b_ih, b_hh);

  // output head
  out_kernel<<<((size_t)N * 64 + 255) / 256, 256, 0, stream>>>(hA, Wo, bo, out_ptr, N);
}

// Round 6
// 900.717 us; speedup vs baseline: 3.6685x; 3.6685x over previous
//
#include <hip/hip_runtime.h>
#include <cstdint>
#include <cstddef>

#define HID 128
#define BSHIFT 7            // 128 nodes per bucket -> nbuck = 782 for N=100000
#define NSB 256             // scatter blocks (pass1/pass2 chunking)

// ---------------- small transpose (weights, once per launch) ----------------
__global__ void transpose_kernel(const float* __restrict__ src, float* __restrict__ dst,
                                 int R, int C) {
  int i = blockIdx.x * blockDim.x + threadIdx.x;
  if (i < R * C) {
    int r = i / C, c = i - r * C;
    dst[c * R + r] = src[i];
  }
}

// ======== deterministic two-pass bucket scatter (NO global atomics) ========
// pass 1: per-block LDS histogram of edge buckets -> countsT[bucket][block]
__global__ __launch_bounds__(256)
void ecount_kernel(const int* __restrict__ row, int* __restrict__ countsT,
                   int E, int nbuck) {
  __shared__ int lh[1024];
  int b = blockIdx.x;
  for (int i = threadIdx.x; i < nbuck; i += 256) lh[i] = 0;
  __syncthreads();
  int per = (E + NSB - 1) / NSB;
  int s = b * per, e = min(s + per, E);
  for (int i = s + (int)threadIdx.x; i < e; i += 256)
    atomicAdd(&lh[row[i] >> BSHIFT], 1);   // LDS atomic, shallow
  __syncthreads();
  for (int i = threadIdx.x; i < nbuck; i += 256) countsT[i * NSB + b] = lh[i];
}

// per-bucket exclusive scan over the NSB block counts (in place) + bucket total
__global__ __launch_bounds__(NSB)
void bprefix_kernel(int* __restrict__ countsT, int* __restrict__ btotal, int nbuck) {
  __shared__ int sd[NSB];
  int bk = blockIdx.x;
  int t = threadIdx.x;
  int v = countsT[bk * NSB + t];
  sd[t] = v;
  __syncthreads();
  for (int off = 1; off < NSB; off <<= 1) {
    int u = (t >= off) ? sd[t - off] : 0;
    __syncthreads();
    sd[t] += u;
    __syncthreads();
  }
  countsT[bk * NSB + t] = sd[t] - v;       // exclusive within bucket
  if (t == NSB - 1) btotal[bk] = sd[t];
}

// exclusive scan of bucket totals -> bstart[0..nbuck]; also offsets[N] = E
__global__ __launch_bounds__(1024)
void bstart_kernel(const int* __restrict__ btotal, int* __restrict__ bstart,
                   int* __restrict__ offsets, int N, int nbuck) {
  __shared__ int sd[1024];
  int t = threadIdx.x;
  int v = (t < nbuck) ? btotal[t] : 0;
  sd[t] = v;
  __syncthreads();
  for (int off = 1; off < 1024; off <<= 1) {
    int u = (t >= off) ? sd[t - off] : 0;
    __syncthreads();
    sd[t] += u;
    __syncthreads();
  }
  if (t < nbuck) bstart[t] = sd[t] - v;
  if (t == nbuck - 1) { bstart[nbuck] = sd[t]; offsets[N] = sd[t]; }
}

// pass 2: write (row,col) pairs to bucket-grouped ebuf at precomputed offsets.
// Only LDS atomics (local rank); global writes land in dense bucket segments.
__global__ __launch_bounds__(256)
void escatter_kernel(const int* __restrict__ row, const int* __restrict__ col,
                     const int* __restrict__ countsT, const int* __restrict__ bstart,
                     int2* __restrict__ ebuf, int E, int nbuck) {
  __shared__ int lcur[1024];
  int b = blockIdx.x;
  for (int i = threadIdx.x; i < nbuck; i += 256)
    lcur[i] = bstart[i] + countsT[i * NSB + b];
  __syncthreads();
  int per = (E + NSB - 1) / NSB;
  int s = b * per, e = min(s + per, E);
  for (int i = s + (int)threadIdx.x; i < e; i += 256) {
    int r = row[i], c = col[i];
    int pos = atomicAdd(&lcur[r >> BSHIFT], 1);
    ebuf[pos] = make_int2(r, c);
  }
}

// pass 3: per-bucket LDS counting sort by row -> CSR (offsets + csrcol).
// ~2K edges over 128 LDS counters; all global writes in the bucket's dense
// 8KB csr_col window. No global atomics anywhere in the CSR build.
__global__ __launch_bounds__(256)
void bsort_kernel(const int2* __restrict__ ebuf, const int* __restrict__ bstart,
                  int* __restrict__ offsets, int* __restrict__ csr_col,
                  int N, int nbuck) {
  __shared__ int cnt[128], off[128], cur[128];
  int bk = blockIdx.x;
  int tid = threadIdx.x;
  int s = bstart[bk], e = bstart[bk + 1];
  if (tid < 128) cnt[tid] = 0;
  __syncthreads();
  for (int i = s + tid; i < e; i += 256)
    atomicAdd(&cnt[ebuf[i].x & 127], 1);
  __syncthreads();
  if (tid < 128) off[tid] = cnt[tid];
  __syncthreads();
  for (int d = 1; d < 128; d <<= 1) {
    int v = 0;
    if (tid < 128 && tid >= d) v = off[tid - d];
    __syncthreads();
    if (tid < 128) off[tid] += v;
    __syncthreads();
  }
  if (tid < 128) {
    int ex = s + off[tid] - cnt[tid];   // exclusive
    cur[tid] = ex;
    int node = (bk << BSHIFT) + tid;
    if (node < N) offsets[node] = ex;
  }
  __syncthreads();
  for (int i = s + tid; i < e; i += 256) {
    int2 rc = ebuf[i];
    int pos = atomicAdd(&cur[rc.x & 127], 1);
    csr_col[pos] = rc.y;
  }
}

// ---------------- edge aggregation: diff[i][d] = sum_e |h[i][d]-h[col][d]| ----
// One wave per node; lane owns dims {lane, lane+64}. Neighbor ids staged into
// registers (coalesced csr_col load + __shfl broadcast); 4-edge unroll gives
// 8 outstanding gathers/lane. REGISTER accumulation (round-5 bagg's LDS-atomic
// variant was 4.6x slower: ds-atomic RMW + single-bank serialization).
__global__ __launch_bounds__(256)
void aggregate_kernel(const float* __restrict__ h, const int* __restrict__ offsets,
                      const int* __restrict__ csr_col, float* __restrict__ diff,
                      int N) {
  int wave = threadIdx.x >> 6;
  int lane = threadIdx.x & 63;
  int node = blockIdx.x * 4 + wave;
  if (node >= N) return;
  int start = offsets[node], end = offsets[node + 1];
  int deg = end - start;
  const float* hrow = h + (size_t)node * HID;
  float hv0 = hrow[lane], hv1 = hrow[lane + 64];
  float a0 = 0.f, a1 = 0.f;

  int batch = min(deg, 64);
  int myc = (lane < batch) ? csr_col[start + lane] : 0;
  int j = 0;
  for (; j + 4 <= batch; j += 4) {
    int c0 = __shfl(myc, j + 0);
    int c1 = __shfl(myc, j + 1);
    int c2 = __shfl(myc, j + 2);
    int c3 = __shfl(myc, j + 3);
    const float* p0 = h + (size_t)c0 * HID;
    const float* p1 = h + (size_t)c1 * HID;
    const float* p2 = h + (size_t)c2 * HID;
    const float* p3 = h + (size_t)c3 * HID;
    float x00 = p0[lane], x01 = p0[lane + 64];
    float x10 = p1[lane], x11 = p1[lane + 64];
    float x20 = p2[lane], x21 = p2[lane + 64];
    float x30 = p3[lane], x31 = p3[lane + 64];
    a0 += fabsf(hv0 - x00) + fabsf(hv0 - x10) + fabsf(hv0 - x20) + fabsf(hv0 - x30);
    a1 += fabsf(hv1 - x01) + fabsf(hv1 - x11) + fabsf(hv1 - x21) + fabsf(hv1 - x31);
  }
  for (; j < batch; ++j) {
    int c = __shfl(myc, j);
    const float* p = h + (size_t)c * HID;
    a0 += fabsf(hv0 - p[lane]);
    a1 += fabsf(hv1 - p[lane + 64]);
  }
  for (int e = start + 64; e < end; ++e) {
    int c = csr_col[e];
    const float* p = h + (size_t)c * HID;
    a0 += fabsf(hv0 - p[lane]);
    a1 += fabsf(hv1 - p[lane + 64]);
  }
  diff[(size_t)node * HID + lane] = a0;
  diff[(size_t)node * HID + lane + 64] = a1;
}

// ---------------- tiled fp32 GEMM: C = relu([A1|A2] @ BT + bias), opt tau ----
// Register-prefetch double-buffer (chunk k+1 loads overlap compute of chunk k).
template<bool TAU>
__global__ __launch_bounds__(256)
void gemm_kernel(const float* __restrict__ A1, const float* __restrict__ A2,
                 const float* __restrict__ BT, const float* __restrict__ bias,
                 float* __restrict__ C, int M, int nchunks,
                 const float* __restrict__ Wt, const float* __restrict__ bt,
                 float* __restrict__ tau_out) {
  __shared__ float As[32][132];   // [k][i], padded leading dim
  __shared__ float Bs[32][128];   // [k][c]
  __shared__ float taured[128];
  int tid = threadIdx.x;
  int tx = tid & 15;   // col group: cols tx + 16*u
  int ty = tid >> 4;   // row group: rows ty*8 + r
  int i0 = blockIdx.x * 128;
  float acc[8][8] = {};
  float4 pa[4], pb[4];

  auto load_chunk = [&](int kc) {
    const float* A = (kc < 4) ? A1 : A2;
    int ksrc = (kc & 3) * 32;
    int kglob = kc * 32;
    #pragma unroll
    for (int q = 0; q < 4; ++q) {
      int f = q * 256 + tid;
      int i = f >> 3;
      int kq = (f & 7) << 2;
      int ig = i0 + i; if (ig >= M) ig = M - 1;
      pa[q] = *(const float4*)(A + (size_t)ig * HID + ksrc + kq);
      int k = f >> 5; int c4 = (f & 31) << 2;
      pb[q] = *(const float4*)(BT + (size_t)(kglob + k) * HID + c4);
    }
  };
  auto stage = [&]() {
    #pragma unroll
    for (int q = 0; q < 4; ++q) {
      int f = q * 256 + tid;
      int i = f >> 3;
      int kq = (f & 7) << 2;
      As[kq + 0][i] = pa[q].x; As[kq + 1][i] = pa[q].y;
      As[kq + 2][i] = pa[q].z; As[kq + 3][i] = pa[q].w;
      int k = f >> 5; int c4 = (f & 31) << 2;
      *(float4*)&Bs[k][c4] = pb[q];
    }
  };

  load_chunk(0);
  for (int kc = 0; kc < nchunks; ++kc) {
    __syncthreads();
    stage();
    __syncthreads();
    if (kc + 1 < nchunks) load_chunk(kc + 1);
    #pragma unroll
    for (int k = 0; k < 32; ++k) {
      float a[8], b[8];
      const float4* ap = (const float4*)&As[k][ty * 8];
      float4 a0 = ap[0], a1 = ap[1];
      a[0]=a0.x; a[1]=a0.y; a[2]=a0.z; a[3]=a0.w;
      a[4]=a1.x; a[5]=a1.y; a[6]=a1.z; a[7]=a1.w;
      #pragma unroll
      for (int u = 0; u < 8; ++u) b[u] = Bs[k][tx + 16 * u];
      #pragma unroll
      for (int r = 0; r < 8; ++r)
        #pragma unroll
        for (int u = 0; u < 8; ++u)
          acc[r][u] = fmaf(a[r], b[u], acc[r][u]);
    }
  }

  float bias_r[8], wt_r[8];
  #pragma unroll
  for (int u = 0; u < 8; ++u) { bias_r[u] = bias[tx + 16 * u]; wt_r[u] = 0.f; }
  if constexpr (TAU) {
    #pragma unroll
    for (int u = 0; u < 8; ++u) wt_r[u] = Wt[tx + 16 * u];
  }
  #pragma unroll
  for (int r = 0; r < 8; ++r) {
    int row = i0 + ty * 8 + r;
    bool ok = row < M;
    float p = 0.f;
    #pragma unroll
    for (int u = 0; u < 8; ++u) {
      float v = fmaxf(acc[r][u] + bias_r[u], 0.f);
      if (ok) C[(size_t)row * HID + tx + 16 * u] = v;
      p = fmaf(v, wt_r[u], p);
    }
    if constexpr (TAU) {
      p += __shfl_down(p, 8);
      p += __shfl_down(p, 4);
      p += __shfl_down(p, 2);
      p += __shfl_down(p, 1);
      if (tx == 0) taured[ty * 8 + r] = p;
    }
  }
  if constexpr (TAU) {
    __syncthreads();
    if (tid < 128) {
      int row = i0 + tid;
      if (row < M) {
        float pre = taured[tid] + bt[0];
        float tau = (pre > 20.f) ? pre : log1pf(expf(pre));
        tau_out[row] = tau;
      }
    }
  }
}

// ---------------- mask + compaction ----------------
// np semantics: floor(1/tau).astype(int32) overflows to INT_MIN for 1/tau >= 2^31
// -> n_updates <= 0 -> NOT masked even though tau < 0.005.
__global__ void compact_kernel(const float* __restrict__ tau, int* __restrict__ list,
                               int* __restrict__ count, int N) {
  for (int i = blockIdx.x * blockDim.x + threadIdx.x; i < N; i += gridDim.x * blockDim.x) {
    float t = tau[i];
    if (t < 0.005f && (1.0f / t) < 2147483648.0f) {
      int p = atomicAdd(count, 1);
      list[p] = i;
    }
  }
}

// ---------------- masked GRU, 16 nodes / block ----------------
__global__ __launch_bounds__(256)
void gru_kernel(const float* __restrict__ diff, float* __restrict__ h,
                const int* __restrict__ list, const int* __restrict__ count,
                const float* __restrict__ WihT, const float* __restrict__ WhhT,
                const float* __restrict__ b_ih, const float* __restrict__ b_hh) {
  int cnt = *count;
  int base = blockIdx.x * 16;
  if (base >= cnt) return;
  __shared__ float dl[16][HID];
  __shared__ float hl[16][HID];
  __shared__ int ids[16];
  int tid = threadIdx.x;
  if (tid < 16) ids[tid] = (base + tid < cnt) ? list[base + tid] : -1;
  __syncthreads();
  #pragma unroll
  for (int q = 0; q < 8; ++q) {
    int f = q * 256 + tid;
    int r = f >> 7, c = f & 127;
    int id = ids[r];
    int src = (id >= 0) ? id : 0;
    dl[r][c] = diff[(size_t)src * HID + c];
    hl[r][c] = h[(size_t)src * HID + c];
  }
  __syncthreads();
  int tx = tid & 127, ty = tid >> 7;
  float air[8] = {}, aiz[8] = {}, ain[8] = {}, ahr[8] = {}, ahz[8] = {}, ahn[8] = {};
  for (int k = 0; k < HID; ++k) {
    float wir = WihT[k * 384 + tx];
    float wiz = WihT[k * 384 + 128 + tx];
    float win = WihT[k * 384 + 256 + tx];
    float whr = WhhT[k * 384 + tx];
    float whz = WhhT[k * 384 + 128 + tx];
    float whn = WhhT[k * 384 + 256 + tx];
    #pragma unroll
    for (int r = 0; r < 8; ++r) {
      float dk = dl[ty * 8 + r][k];
      float hk = hl[ty * 8 + r][k];
      air[r] = fmaf(dk, wir, air[r]);
      aiz[r] = fmaf(dk, wiz, aiz[r]);
      ain[r] = fmaf(dk, win, ain[r]);
      ahr[r] = fmaf(hk, whr, ahr[r]);
      ahz[r] = fmaf(hk, whz, ahz[r]);
      ahn[r] = fmaf(hk, whn, ahn[r]);
    }
  }
  float bir = b_ih[tx], biz = b_ih[128 + tx], bin = b_ih[256 + tx];
  float bhr = b_hh[tx], bhz = b_hh[128 + tx], bhn = b_hh[256 + tx];
  #pragma unroll
  for (int r = 0; r < 8; ++r) {
    int id = ids[ty * 8 + r];
    if (id < 0) continue;
    float rg = 1.f / (1.f + expf(-((air[r] + bir) + (ahr[r] + bhr))));
    float z  = 1.f / (1.f + expf(-((aiz[r] + biz) + (ahz[r] + bhz))));
    float n  = tanhf((ain[r] + bin) + rg * (ahn[r] + bhn));
    float hv = hl[ty * 8 + r][tx];
    h[(size_t)id * HID + tx] = (1.f - z) * n + z * hv;
  }
}

// ---------------- output head: out = h @ Wo^T + bo  (wave per node) ----------
__global__ void out_kernel(const float* __restrict__ h, const float* __restrict__ Wo,
                           const float* __restrict__ bo, float* __restrict__ out, int N) {
  int g = blockIdx.x * blockDim.x + threadIdx.x;
  int node = g >> 6;
  int lane = threadIdx.x & 63;
  if (node >= N) return;
  float h0 = h[(size_t)node * HID + lane];
  float h1 = h[(size_t)node * HID + 64 + lane];
  float s0 = h0 * Wo[lane] + h1 * Wo[64 + lane];
  float s1 = h0 * Wo[128 + lane] + h1 * Wo[192 + lane];
  for (int d = 32; d; d >>= 1) {
    s0 += __shfl_down(s0, d);
    s1 += __shfl_down(s1, d);
  }
  if (lane == 0) {
    out[(size_t)node * 2 + 0] = s0 + bo[0];
    out[(size_t)node * 2 + 1] = s1 + bo[1];
  }
}

extern "C" void kernel_launch(void* const* d_in, const int* in_sizes, int n_in,
                              void* d_out, int out_size, void* d_ws, size_t ws_size,
                              hipStream_t stream) {
  const float* x    = (const float*)d_in[0];
  const int*   ei   = (const int*)d_in[1];
  const float* W_in = (const float*)d_in[2];
  const float* b_in = (const float*)d_in[3];
  const float* Wd   = (const float*)d_in[4];
  const float* bd   = (const float*)d_in[5];
  const float* Wt   = (const float*)d_in[6];
  const float* bt   = (const float*)d_in[7];
  const float* W_ih = (const float*)d_in[8];
  const float* W_hh = (const float*)d_in[9];
  const float* b_ih = (const float*)d_in[10];
  const float* b_hh = (const float*)d_in[11];
  const float* Wo   = (const float*)d_in[12];
  const float* bo   = (const float*)d_in[13];

  const int N = in_sizes[0] / HID;      // 100000
  const int E = in_sizes[1] / 2;        // 1600000
  const int* rowp = ei;
  const int* colp = ei + E;
  const int nbuck = (N + (1 << BSHIFT) - 1) >> BSHIFT;   // 782 (<=1024)

  // workspace carve-up (256B aligned)
  char* p = (char*)d_ws;
  auto alloc = [&](size_t bytes) { void* r = (void*)p; p += (bytes + 255) & ~(size_t)255; return r; };
  float* hA     = (float*)alloc((size_t)N * HID * 4);
  float* hB     = (float*)alloc((size_t)N * HID * 4);
  float* diff   = (float*)alloc((size_t)N * HID * 4);
  float* WinT   = (float*)alloc(128 * 128 * 4);
  float* WdT0   = (float*)alloc(256 * 128 * 4);
  float* WdT1   = (float*)alloc(256 * 128 * 4);
  float* WihT   = (float*)alloc(128 * 384 * 4);
  float* WhhT   = (float*)alloc(128 * 384 * 4);
  float* tau0   = (float*)alloc((size_t)N * 4);
  int*   list   = (int*)alloc((size_t)N * 4);
  int*   count  = (int*)alloc(256);
  int*   countsT= (int*)alloc((size_t)1024 * NSB * 4);
  int*   btotal = (int*)alloc(1024 * 4);
  int*   bstart = (int*)alloc(1028 * 4);
  int*   offs   = (int*)alloc(((size_t)N + 1) * 4);
  int*   csrcol = (int*)alloc((size_t)E * 4);
  int2*  ebuf   = (int2*)alloc((size_t)E * 8);

  float* out_ptr = (float*)d_out;            // [N,2] flat
  float* tau_out = (float*)d_out + (size_t)N * 2;  // [N]

  // weight transposes
  transpose_kernel<<<(128 * 128 + 255) / 256, 256, 0, stream>>>(W_in, WinT, 128, 128);
  transpose_kernel<<<(128 * 256 + 255) / 256, 256, 0, stream>>>(Wd, WdT0, 128, 256);
  transpose_kernel<<<(128 * 256 + 255) / 256, 256, 0, stream>>>(Wd + 128 * 256, WdT1, 128, 256);
  transpose_kernel<<<(384 * 128 + 255) / 256, 256, 0, stream>>>(W_ih, WihT, 384, 128);
  transpose_kernel<<<(384 * 128 + 255) / 256, 256, 0, stream>>>(W_hh, WhhT, 384, 128);

  // CSR build, no global atomics (reused by both layers)
  ecount_kernel<<<NSB, 256, 0, stream>>>(rowp, countsT, E, nbuck);
  bprefix_kernel<<<nbuck, NSB, 0, stream>>>(countsT, btotal, nbuck);
  bstart_kernel<<<1, 1024, 0, stream>>>(btotal, bstart, offs, N, nbuck);
  escatter_kernel<<<NSB, 256, 0, stream>>>(rowp, colp, countsT, bstart, ebuf, E, nbuck);
  bsort_kernel<<<nbuck, 256, 0, stream>>>(ebuf, bstart, offs, csrcol, N, nbuck);

  const int gemm_blocks = (N + 127) / 128;
  const int agg_blocks = (N + 3) / 4;

  // input layer: hA = relu(x @ Win^T + b_in)
  gemm_kernel<false><<<gemm_blocks, 256, 0, stream>>>(
      x, nullptr, WinT, b_in, hA, N, 4, nullptr, nullptr, nullptr);

  // ---- layer 0 ----
  aggregate_kernel<<<agg_blocks, 256, 0, stream>>>(hA, offs, csrcol, diff, N);
  gemm_kernel<true><<<gemm_blocks, 256, 0, stream>>>(
      hA, diff, WdT0, bd, hB, N, 8, Wt, bt, tau0);
  hipMemsetAsync(count, 0, 4, stream);
  compact_kernel<<<(N + 255) / 256, 256, 0, stream>>>(tau0, list, count, N);
  gru_kernel<<<(N + 15) / 16, 256, 0, stream>>>(diff, hB, list, count, WihT, WhhT, b_ih, b_hh);

  // ---- layer 1 ----
  aggregate_kernel<<<agg_blocks, 256, 0, stream>>>(hB, offs, csrcol, diff, N);
  gemm_kernel<true><<<gemm_blocks, 256, 0, stream>>>(
      hB, diff, WdT1, bd + 128, hA, N, 8, Wt, bt, tau_out);
  hipMemsetAsync(count, 0, 4, stream);
  compact_kernel<<<(N + 255) / 256, 256, 0, stream>>>(tau_out, list, count, N);
  gru_kernel<<<(N + 15) / 16, 256, 0, stream>>>(diff, hA, list, count, WihT, WhhT, b_ih, b_hh);

  // output head
  out_kernel<<<((size_t)N * 64 + 255) / 256, 256, 0, stream>>>(hA, Wo, bo, out_ptr, N);
}

// Round 7
// 798.513 us; speedup vs baseline: 4.1380x; 1.1280x over previous
//
#include <hip/hip_runtime.h>
#include <cstdint>
#include <cstddef>

#define HID 128
#define BSHIFT 7            // 128 nodes per bucket -> nbuck = 782 for N=100000
#define NSB 256             // scatter blocks (pass1/pass2 chunking)

// ---------------- small transpose (weights, once per launch) ----------------
__global__ void transpose_kernel(const float* __restrict__ src, float* __restrict__ dst,
                                 int R, int C) {
  int i = blockIdx.x * blockDim.x + threadIdx.x;
  if (i < R * C) {
    int r = i / C, c = i - r * C;
    dst[c * R + r] = src[i];
  }
}

// ======== deterministic two-pass bucket scatter (NO global atomics) ========
__global__ __launch_bounds__(256)
void ecount_kernel(const int* __restrict__ row, int* __restrict__ countsT,
                   int E, int nbuck) {
  __shared__ int lh[1024];
  int b = blockIdx.x;
  for (int i = threadIdx.x; i < nbuck; i += 256) lh[i] = 0;
  __syncthreads();
  int per = (E + NSB - 1) / NSB;
  int s = b * per, e = min(s + per, E);
  for (int i = s + (int)threadIdx.x; i < e; i += 256)
    atomicAdd(&lh[row[i] >> BSHIFT], 1);   // LDS atomic, shallow
  __syncthreads();
  for (int i = threadIdx.x; i < nbuck; i += 256) countsT[i * NSB + b] = lh[i];
}

__global__ __launch_bounds__(NSB)
void bprefix_kernel(int* __restrict__ countsT, int* __restrict__ btotal, int nbuck) {
  __shared__ int sd[NSB];
  int bk = blockIdx.x;
  int t = threadIdx.x;
  int v = countsT[bk * NSB + t];
  sd[t] = v;
  __syncthreads();
  for (int off = 1; off < NSB; off <<= 1) {
    int u = (t >= off) ? sd[t - off] : 0;
    __syncthreads();
    sd[t] += u;
    __syncthreads();
  }
  countsT[bk * NSB + t] = sd[t] - v;       // exclusive within bucket
  if (t == NSB - 1) btotal[bk] = sd[t];
}

__global__ __launch_bounds__(1024)
void bstart_kernel(const int* __restrict__ btotal, int* __restrict__ bstart,
                   int* __restrict__ offsets, int N, int nbuck) {
  __shared__ int sd[1024];
  int t = threadIdx.x;
  int v = (t < nbuck) ? btotal[t] : 0;
  sd[t] = v;
  __syncthreads();
  for (int off = 1; off < 1024; off <<= 1) {
    int u = (t >= off) ? sd[t - off] : 0;
    __syncthreads();
    sd[t] += u;
    __syncthreads();
  }
  if (t < nbuck) bstart[t] = sd[t] - v;
  if (t == nbuck - 1) { bstart[nbuck] = sd[t]; offsets[N] = sd[t]; }
}

__global__ __launch_bounds__(256)
void escatter_kernel(const int* __restrict__ row, const int* __restrict__ col,
                     const int* __restrict__ countsT, const int* __restrict__ bstart,
                     int2* __restrict__ ebuf, int E, int nbuck) {
  __shared__ int lcur[1024];
  int b = blockIdx.x;
  for (int i = threadIdx.x; i < nbuck; i += 256)
    lcur[i] = bstart[i] + countsT[i * NSB + b];
  __syncthreads();
  int per = (E + NSB - 1) / NSB;
  int s = b * per, e = min(s + per, E);
  for (int i = s + (int)threadIdx.x; i < e; i += 256) {
    int r = row[i], c = col[i];
    int pos = atomicAdd(&lcur[r >> BSHIFT], 1);
    ebuf[pos] = make_int2(r, c);
  }
}

// pass 3: per-bucket LDS counting sort by row -> CSR (offsets + csrcol)
__global__ __launch_bounds__(256)
void bsort_kernel(const int2* __restrict__ ebuf, const int* __restrict__ bstart,
                  int* __restrict__ offsets, int* __restrict__ csr_col,
                  int N, int nbuck) {
  __shared__ int cnt[128], off[128], cur[128];
  int bk = blockIdx.x;
  int tid = threadIdx.x;
  int s = bstart[bk], e = bstart[bk + 1];
  if (tid < 128) cnt[tid] = 0;
  __syncthreads();
  for (int i = s + tid; i < e; i += 256)
    atomicAdd(&cnt[ebuf[i].x & 127], 1);
  __syncthreads();
  if (tid < 128) off[tid] = cnt[tid];
  __syncthreads();
  for (int d = 1; d < 128; d <<= 1) {
    int v = 0;
    if (tid < 128 && tid >= d) v = off[tid - d];
    __syncthreads();
    if (tid < 128) off[tid] += v;
    __syncthreads();
  }
  if (tid < 128) {
    int ex = s + off[tid] - cnt[tid];   // exclusive
    cur[tid] = ex;
    int node = (bk << BSHIFT) + tid;
    if (node < N) offsets[node] = ex;
  }
  __syncthreads();
  for (int i = s + tid; i < e; i += 256) {
    int2 rc = ebuf[i];
    int pos = atomicAdd(&cur[rc.x & 127], 1);
    csr_col[pos] = rc.y;
  }
}

// ---------------- edge aggregation: diff[i][d] = sum_e |h[i][d]-h[col][d]| ----
// One wave per node; lane owns dims {lane, lane+64}. Register accumulation;
// 8-edge unroll = 16 outstanding gathers/lane (L2-miss/L3-fill bound; deeper
// MLP to saturate fill bandwidth).
__global__ __launch_bounds__(256)
void aggregate_kernel(const float* __restrict__ h, const int* __restrict__ offsets,
                      const int* __restrict__ csr_col, float* __restrict__ diff,
                      int N) {
  int wave = threadIdx.x >> 6;
  int lane = threadIdx.x & 63;
  int node = blockIdx.x * 4 + wave;
  if (node >= N) return;
  int start = offsets[node], end = offsets[node + 1];
  int deg = end - start;
  const float* hrow = h + (size_t)node * HID;
  float hv0 = hrow[lane], hv1 = hrow[lane + 64];
  float a0 = 0.f, a1 = 0.f;

  int batch = min(deg, 64);
  int myc = (lane < batch) ? csr_col[start + lane] : 0;
  int j = 0;
  for (; j + 8 <= batch; j += 8) {
    const float* p0 = h + (size_t)__shfl(myc, j + 0) * HID;
    const float* p1 = h + (size_t)__shfl(myc, j + 1) * HID;
    const float* p2 = h + (size_t)__shfl(myc, j + 2) * HID;
    const float* p3 = h + (size_t)__shfl(myc, j + 3) * HID;
    const float* p4 = h + (size_t)__shfl(myc, j + 4) * HID;
    const float* p5 = h + (size_t)__shfl(myc, j + 5) * HID;
    const float* p6 = h + (size_t)__shfl(myc, j + 6) * HID;
    const float* p7 = h + (size_t)__shfl(myc, j + 7) * HID;
    float x00 = p0[lane], x01 = p0[lane + 64];
    float x10 = p1[lane], x11 = p1[lane + 64];
    float x20 = p2[lane], x21 = p2[lane + 64];
    float x30 = p3[lane], x31 = p3[lane + 64];
    float x40 = p4[lane], x41 = p4[lane + 64];
    float x50 = p5[lane], x51 = p5[lane + 64];
    float x60 = p6[lane], x61 = p6[lane + 64];
    float x70 = p7[lane], x71 = p7[lane + 64];
    a0 += fabsf(hv0 - x00) + fabsf(hv0 - x10) + fabsf(hv0 - x20) + fabsf(hv0 - x30)
        + fabsf(hv0 - x40) + fabsf(hv0 - x50) + fabsf(hv0 - x60) + fabsf(hv0 - x70);
    a1 += fabsf(hv1 - x01) + fabsf(hv1 - x11) + fabsf(hv1 - x21) + fabsf(hv1 - x31)
        + fabsf(hv1 - x41) + fabsf(hv1 - x51) + fabsf(hv1 - x61) + fabsf(hv1 - x71);
  }
  for (; j < batch; ++j) {
    const float* p = h + (size_t)__shfl(myc, j) * HID;
    a0 += fabsf(hv0 - p[lane]);
    a1 += fabsf(hv1 - p[lane + 64]);
  }
  for (int e = start + 64; e < end; ++e) {
    int c = csr_col[e];
    const float* p = h + (size_t)c * HID;
    a0 += fabsf(hv0 - p[lane]);
    a1 += fabsf(hv1 - p[lane + 64]);
  }
  diff[(size_t)node * HID + lane] = a0;
  diff[(size_t)node * HID + lane + 64] = a1;
}

// ---------------- tiled fp32 GEMM: C = relu([A1|A2] @ BT + bias), opt tau ----
// Round-3 form. NOTE: register-prefetch double-buffer variant (round 6) took
// VGPR 84->148, occupancy 19->8.6%, and REGRESSED 131->177us. Keep simple.
template<bool TAU>
__global__ __launch_bounds__(256)
void gemm_kernel(const float* __restrict__ A1, const float* __restrict__ A2,
                 const float* __restrict__ BT, const float* __restrict__ bias,
                 float* __restrict__ C, int M, int nchunks,
                 const float* __restrict__ Wt, const float* __restrict__ bt,
                 float* __restrict__ tau_out) {
  __shared__ float As[32][132];   // [k][i], padded leading dim
  __shared__ float Bs[32][128];   // [k][c]
  __shared__ float taured[128];
  int tid = threadIdx.x;
  int tx = tid & 15;   // col group: cols tx + 16*u
  int ty = tid >> 4;   // row group: rows ty*8 + r
  int i0 = blockIdx.x * 128;
  float acc[8][8] = {};

  for (int kc = 0; kc < nchunks; ++kc) {
    const float* A = (kc < 4) ? A1 : A2;
    int ksrc = (kc & 3) * 32;
    int kglob = kc * 32;
    #pragma unroll
    for (int q = 0; q < 4; ++q) {     // stage A (transposed into LDS)
      int f = q * 256 + tid;
      int i = f >> 3;
      int kq = (f & 7) << 2;
      int ig = i0 + i; if (ig >= M) ig = M - 1;
      float4 v = *(const float4*)(A + (size_t)ig * HID + ksrc + kq);
      As[kq + 0][i] = v.x; As[kq + 1][i] = v.y;
      As[kq + 2][i] = v.z; As[kq + 3][i] = v.w;
    }
    #pragma unroll
    for (int q = 0; q < 4; ++q) {     // stage B
      int f = q * 256 + tid;
      int k = f >> 5; int c4 = (f & 31) << 2;
      *(float4*)&Bs[k][c4] = *(const float4*)(BT + (size_t)(kglob + k) * HID + c4);
    }
    __syncthreads();
    #pragma unroll
    for (int k = 0; k < 32; ++k) {
      float a[8], b[8];
      const float4* ap = (const float4*)&As[k][ty * 8];
      float4 a0 = ap[0], a1 = ap[1];
      a[0]=a0.x; a[1]=a0.y; a[2]=a0.z; a[3]=a0.w;
      a[4]=a1.x; a[5]=a1.y; a[6]=a1.z; a[7]=a1.w;
      #pragma unroll
      for (int u = 0; u < 8; ++u) b[u] = Bs[k][tx + 16 * u];
      #pragma unroll
      for (int r = 0; r < 8; ++r)
        #pragma unroll
        for (int u = 0; u < 8; ++u)
          acc[r][u] = fmaf(a[r], b[u], acc[r][u]);
    }
    __syncthreads();
  }

  float bias_r[8], wt_r[8];
  #pragma unroll
  for (int u = 0; u < 8; ++u) { bias_r[u] = bias[tx + 16 * u]; wt_r[u] = 0.f; }
  if constexpr (TAU) {
    #pragma unroll
    for (int u = 0; u < 8; ++u) wt_r[u] = Wt[tx + 16 * u];
  }
  #pragma unroll
  for (int r = 0; r < 8; ++r) {
    int row = i0 + ty * 8 + r;
    bool ok = row < M;
    float p = 0.f;
    #pragma unroll
    for (int u = 0; u < 8; ++u) {
      float v = fmaxf(acc[r][u] + bias_r[u], 0.f);
      if (ok) C[(size_t)row * HID + tx + 16 * u] = v;
      p = fmaf(v, wt_r[u], p);
    }
    if constexpr (TAU) {
      p += __shfl_down(p, 8);
      p += __shfl_down(p, 4);
      p += __shfl_down(p, 2);
      p += __shfl_down(p, 1);
      if (tx == 0) taured[ty * 8 + r] = p;
    }
  }
  if constexpr (TAU) {
    __syncthreads();
    if (tid < 128) {
      int row = i0 + tid;
      if (row < M) {
        float pre = taured[tid] + bt[0];
        float tau = (pre > 20.f) ? pre : log1pf(expf(pre));
        tau_out[row] = tau;
      }
    }
  }
}

// ---------------- mask + compaction ----------------
// np semantics: floor(1/tau).astype(int32) overflows to INT_MIN for 1/tau >= 2^31
// -> n_updates <= 0 -> NOT masked even though tau < 0.005.
__global__ void compact_kernel(const float* __restrict__ tau, int* __restrict__ list,
                               int* __restrict__ count, int N) {
  for (int i = blockIdx.x * blockDim.x + threadIdx.x; i < N; i += gridDim.x * blockDim.x) {
    float t = tau[i];
    if (t < 0.005f && (1.0f / t) < 2147483648.0f) {
      int p = atomicAdd(count, 1);
      list[p] = i;
    }
  }
}

// ---------------- masked GRU, 16 nodes / block ----------------
__global__ __launch_bounds__(256)
void gru_kernel(const float* __restrict__ diff, float* __restrict__ h,
                const int* __restrict__ list, const int* __restrict__ count,
                const float* __restrict__ WihT, const float* __restrict__ WhhT,
                const float* __restrict__ b_ih, const float* __restrict__ b_hh) {
  int cnt = *count;
  int base = blockIdx.x * 16;
  if (base >= cnt) return;
  __shared__ float dl[16][HID];
  __shared__ float hl[16][HID];
  __shared__ int ids[16];
  int tid = threadIdx.x;
  if (tid < 16) ids[tid] = (base + tid < cnt) ? list[base + tid] : -1;
  __syncthreads();
  #pragma unroll
  for (int q = 0; q < 8; ++q) {
    int f = q * 256 + tid;
    int r = f >> 7, c = f & 127;
    int id = ids[r];
    int src = (id >= 0) ? id : 0;
    dl[r][c] = diff[(size_t)src * HID + c];
    hl[r][c] = h[(size_t)src * HID + c];
  }
  __syncthreads();
  int tx = tid & 127, ty = tid >> 7;
  float air[8] = {}, aiz[8] = {}, ain[8] = {}, ahr[8] = {}, ahz[8] = {}, ahn[8] = {};
  for (int k = 0; k < HID; ++k) {
    float wir = WihT[k * 384 + tx];
    float wiz = WihT[k * 384 + 128 + tx];
    float win = WihT[k * 384 + 256 + tx];
    float whr = WhhT[k * 384 + tx];
    float whz = WhhT[k * 384 + 128 + tx];
    float whn = WhhT[k * 384 + 256 + tx];
    #pragma unroll
    for (int r = 0; r < 8; ++r) {
      float dk = dl[ty * 8 + r][k];
      float hk = hl[ty * 8 + r][k];
      air[r] = fmaf(dk, wir, air[r]);
      aiz[r] = fmaf(dk, wiz, aiz[r]);
      ain[r] = fmaf(dk, win, ain[r]);
      ahr[r] = fmaf(hk, whr, ahr[r]);
      ahz[r] = fmaf(hk, whz, ahz[r]);
      ahn[r] = fmaf(hk, whn, ahn[r]);
    }
  }
  float bir = b_ih[tx], biz = b_ih[128 + tx], bin = b_ih[256 + tx];
  float bhr = b_hh[tx], bhz = b_hh[128 + tx], bhn = b_hh[256 + tx];
  #pragma unroll
  for (int r = 0; r < 8; ++r) {
    int id = ids[ty * 8 + r];
    if (id < 0) continue;
    float rg = 1.f / (1.f + expf(-((air[r] + bir) + (ahr[r] + bhr))));
    float z  = 1.f / (1.f + expf(-((aiz[r] + biz) + (ahz[r] + bhz))));
    float n  = tanhf((ain[r] + bin) + rg * (ahn[r] + bhn));
    float hv = hl[ty * 8 + r][tx];
    h[(size_t)id * HID + tx] = (1.f - z) * n + z * hv;
  }
}

// ---------------- output head: out = h @ Wo^T + bo  (wave per node) ----------
__global__ void out_kernel(const float* __restrict__ h, const float* __restrict__ Wo,
                           const float* __restrict__ bo, float* __restrict__ out, int N) {
  int g = blockIdx.x * blockDim.x + threadIdx.x;
  int node = g >> 6;
  int lane = threadIdx.x & 63;
  if (node >= N) return;
  float h0 = h[(size_t)node * HID + lane];
  float h1 = h[(size_t)node * HID + 64 + lane];
  float s0 = h0 * Wo[lane] + h1 * Wo[64 + lane];
  float s1 = h0 * Wo[128 + lane] + h1 * Wo[192 + lane];
  for (int d = 32; d; d >>= 1) {
    s0 += __shfl_down(s0, d);
    s1 += __shfl_down(s1, d);
  }
  if (lane == 0) {
    out[(size_t)node * 2 + 0] = s0 + bo[0];
    out[(size_t)node * 2 + 1] = s1 + bo[1];
  }
}

extern "C" void kernel_launch(void* const* d_in, const int* in_sizes, int n_in,
                              void* d_out, int out_size, void* d_ws, size_t ws_size,
                              hipStream_t stream) {
  const float* x    = (const float*)d_in[0];
  const int*   ei   = (const int*)d_in[1];
  const float* W_in = (const float*)d_in[2];
  const float* b_in = (const float*)d_in[3];
  const float* Wd   = (const float*)d_in[4];
  const float* bd   = (const float*)d_in[5];
  const float* Wt   = (const float*)d_in[6];
  const float* bt   = (const float*)d_in[7];
  const float* W_ih = (const float*)d_in[8];
  const float* W_hh = (const float*)d_in[9];
  const float* b_ih = (const float*)d_in[10];
  const float* b_hh = (const float*)d_in[11];
  const float* Wo   = (const float*)d_in[12];
  const float* bo   = (const float*)d_in[13];

  const int N = in_sizes[0] / HID;      // 100000
  const int E = in_sizes[1] / 2;        // 1600000
  const int* rowp = ei;
  const int* colp = ei + E;
  const int nbuck = (N + (1 << BSHIFT) - 1) >> BSHIFT;   // 782 (<=1024)

  // workspace carve-up (256B aligned)
  char* p = (char*)d_ws;
  auto alloc = [&](size_t bytes) { void* r = (void*)p; p += (bytes + 255) & ~(size_t)255; return r; };
  float* hA     = (float*)alloc((size_t)N * HID * 4);
  float* hB     = (float*)alloc((size_t)N * HID * 4);
  float* diff   = (float*)alloc((size_t)N * HID * 4);
  float* WinT   = (float*)alloc(128 * 128 * 4);
  float* WdT0   = (float*)alloc(256 * 128 * 4);
  float* WdT1   = (float*)alloc(256 * 128 * 4);
  float* WihT   = (float*)alloc(128 * 384 * 4);
  float* WhhT   = (float*)alloc(128 * 384 * 4);
  float* tau0   = (float*)alloc((size_t)N * 4);
  int*   list   = (int*)alloc((size_t)N * 4);
  int*   count  = (int*)alloc(256);
  int*   countsT= (int*)alloc((size_t)1024 * NSB * 4);
  int*   btotal = (int*)alloc(1024 * 4);
  int*   bstart = (int*)alloc(1028 * 4);
  int*   offs   = (int*)alloc(((size_t)N + 1) * 4);
  int*   csrcol = (int*)alloc((size_t)E * 4);
  int2*  ebuf   = (int2*)alloc((size_t)E * 8);

  float* out_ptr = (float*)d_out;            // [N,2] flat
  float* tau_out = (float*)d_out + (size_t)N * 2;  // [N]

  // weight transposes
  transpose_kernel<<<(128 * 128 + 255) / 256, 256, 0, stream>>>(W_in, WinT, 128, 128);
  transpose_kernel<<<(128 * 256 + 255) / 256, 256, 0, stream>>>(Wd, WdT0, 128, 256);
  transpose_kernel<<<(128 * 256 + 255) / 256, 256, 0, stream>>>(Wd + 128 * 256, WdT1, 128, 256);
  transpose_kernel<<<(384 * 128 + 255) / 256, 256, 0, stream>>>(W_ih, WihT, 384, 128);
  transpose_kernel<<<(384 * 128 + 255) / 256, 256, 0, stream>>>(W_hh, WhhT, 384, 128);

  // CSR build, no global atomics (reused by both layers)
  ecount_kernel<<<NSB, 256, 0, stream>>>(rowp, countsT, E, nbuck);
  bprefix_kernel<<<nbuck, NSB, 0, stream>>>(countsT, btotal, nbuck);
  bstart_kernel<<<1, 1024, 0, stream>>>(btotal, bstart, offs, N, nbuck);
  escatter_kernel<<<NSB, 256, 0, stream>>>(rowp, colp, countsT, bstart, ebuf, E, nbuck);
  bsort_kernel<<<nbuck, 256, 0, stream>>>(ebuf, bstart, offs, csrcol, N, nbuck);

  const int gemm_blocks = (N + 127) / 128;
  const int agg_blocks = (N + 3) / 4;

  // input layer: hA = relu(x @ Win^T + b_in)
  gemm_kernel<false><<<gemm_blocks, 256, 0, stream>>>(
      x, nullptr, WinT, b_in, hA, N, 4, nullptr, nullptr, nullptr);

  // ---- layer 0 ----
  aggregate_kernel<<<agg_blocks, 256, 0, stream>>>(hA, offs, csrcol, diff, N);
  gemm_kernel<true><<<gemm_blocks, 256, 0, stream>>>(
      hA, diff, WdT0, bd, hB, N, 8, Wt, bt, tau0);
  hipMemsetAsync(count, 0, 4, stream);
  compact_kernel<<<(N + 255) / 256, 256, 0, stream>>>(tau0, list, count, N);
  gru_kernel<<<(N + 15) / 16, 256, 0, stream>>>(diff, hB, list, count, WihT, WhhT, b_ih, b_hh);

  // ---- layer 1 ----
  aggregate_kernel<<<agg_blocks, 256, 0, stream>>>(hB, offs, csrcol, diff, N);
  gemm_kernel<true><<<gemm_blocks, 256, 0, stream>>>(
      hB, diff, WdT1, bd + 128, hA, N, 8, Wt, bt, tau_out);
  hipMemsetAsync(count, 0, 4, stream);
  compact_kernel<<<(N + 255) / 256, 256, 0, stream>>>(tau_out, list, count, N);
  gru_kernel<<<(N + 15) / 16, 256, 0, stream>>>(diff, hA, list, count, WihT, WhhT, b_ih, b_hh);

  // output head
  out_kernel<<<((size_t)N * 64 + 255) / 256, 256, 0, stream>>>(hA, Wo, bo, out_ptr, N);
}

// Round 8
// 759.831 us; speedup vs baseline: 4.3487x; 1.0509x over previous
//
#include <hip/hip_runtime.h>
#include <cstdint>
#include <cstddef>

#define HID 128
#define BSHIFT 7            // 128 nodes per bucket -> nbuck = 782 for N=100000
#define NSB 256             // scatter blocks (pass1/pass2 chunking)

// ---------------- small transpose (weights, once per launch) ----------------
__global__ void transpose_kernel(const float* __restrict__ src, float* __restrict__ dst,
                                 int R, int C) {
  int i = blockIdx.x * blockDim.x + threadIdx.x;
  if (i < R * C) {
    int r = i / C, c = i - r * C;
    dst[c * R + r] = src[i];
  }
}

// ======== deterministic two-pass bucket scatter (NO global atomics) ========
__global__ __launch_bounds__(256)
void ecount_kernel(const int* __restrict__ row, int* __restrict__ countsT,
                   int E, int nbuck) {
  __shared__ int lh[1024];
  int b = blockIdx.x;
  for (int i = threadIdx.x; i < nbuck; i += 256) lh[i] = 0;
  __syncthreads();
  int per = (E + NSB - 1) / NSB;
  int s = b * per, e = min(s + per, E);
  for (int i = s + (int)threadIdx.x; i < e; i += 256)
    atomicAdd(&lh[row[i] >> BSHIFT], 1);   // LDS atomic, shallow
  __syncthreads();
  for (int i = threadIdx.x; i < nbuck; i += 256) countsT[i * NSB + b] = lh[i];
}

__global__ __launch_bounds__(NSB)
void bprefix_kernel(int* __restrict__ countsT, int* __restrict__ btotal, int nbuck) {
  __shared__ int sd[NSB];
  int bk = blockIdx.x;
  int t = threadIdx.x;
  int v = countsT[bk * NSB + t];
  sd[t] = v;
  __syncthreads();
  for (int off = 1; off < NSB; off <<= 1) {
    int u = (t >= off) ? sd[t - off] : 0;
    __syncthreads();
    sd[t] += u;
    __syncthreads();
  }
  countsT[bk * NSB + t] = sd[t] - v;       // exclusive within bucket
  if (t == NSB - 1) btotal[bk] = sd[t];
}

__global__ __launch_bounds__(1024)
void bstart_kernel(const int* __restrict__ btotal, int* __restrict__ bstart,
                   int* __restrict__ offsets, int N, int nbuck) {
  __shared__ int sd[1024];
  int t = threadIdx.x;
  int v = (t < nbuck) ? btotal[t] : 0;
  sd[t] = v;
  __syncthreads();
  for (int off = 1; off < 1024; off <<= 1) {
    int u = (t >= off) ? sd[t - off] : 0;
    __syncthreads();
    sd[t] += u;
    __syncthreads();
  }
  if (t < nbuck) bstart[t] = sd[t] - v;
  if (t == nbuck - 1) { bstart[nbuck] = sd[t]; offsets[N] = sd[t]; }
}

__global__ __launch_bounds__(256)
void escatter_kernel(const int* __restrict__ row, const int* __restrict__ col,
                     const int* __restrict__ countsT, const int* __restrict__ bstart,
                     int2* __restrict__ ebuf, int E, int nbuck) {
  __shared__ int lcur[1024];
  int b = blockIdx.x;
  for (int i = threadIdx.x; i < nbuck; i += 256)
    lcur[i] = bstart[i] + countsT[i * NSB + b];
  __syncthreads();
  int per = (E + NSB - 1) / NSB;
  int s = b * per, e = min(s + per, E);
  for (int i = s + (int)threadIdx.x; i < e; i += 256) {
    int r = row[i], c = col[i];
    int pos = atomicAdd(&lcur[r >> BSHIFT], 1);
    ebuf[pos] = make_int2(r, c);
  }
}

// pass 3: per-bucket LDS counting sort by row -> CSR (offsets + csrcol)
__global__ __launch_bounds__(256)
void bsort_kernel(const int2* __restrict__ ebuf, const int* __restrict__ bstart,
                  int* __restrict__ offsets, int* __restrict__ csr_col,
                  int N, int nbuck) {
  __shared__ int cnt[128], off[128], cur[128];
  int bk = blockIdx.x;
  int tid = threadIdx.x;
  int s = bstart[bk], e = bstart[bk + 1];
  if (tid < 128) cnt[tid] = 0;
  __syncthreads();
  for (int i = s + tid; i < e; i += 256)
    atomicAdd(&cnt[ebuf[i].x & 127], 1);
  __syncthreads();
  if (tid < 128) off[tid] = cnt[tid];
  __syncthreads();
  for (int d = 1; d < 128; d <<= 1) {
    int v = 0;
    if (tid < 128 && tid >= d) v = off[tid - d];
    __syncthreads();
    if (tid < 128) off[tid] += v;
    __syncthreads();
  }
  if (tid < 128) {
    int ex = s + off[tid] - cnt[tid];   // exclusive
    cur[tid] = ex;
    int node = (bk << BSHIFT) + tid;
    if (node < N) offsets[node] = ex;
  }
  __syncthreads();
  for (int i = s + tid; i < e; i += 256) {
    int2 rc = ebuf[i];
    int pos = atomicAdd(&cur[rc.x & 127], 1);
    csr_col[pos] = rc.y;
  }
}

// ---------------- edge aggregation: diff[i][d] = sum_e |h[i][d]-h[col][d]| ----
// One wave per node; lane owns dims {lane, lane+64}. Register accumulation;
// 8-edge unroll = 16 outstanding gathers/lane.
__global__ __launch_bounds__(256)
void aggregate_kernel(const float* __restrict__ h, const int* __restrict__ offsets,
                      const int* __restrict__ csr_col, float* __restrict__ diff,
                      int N) {
  int wave = threadIdx.x >> 6;
  int lane = threadIdx.x & 63;
  int node = blockIdx.x * 4 + wave;
  if (node >= N) return;
  int start = offsets[node], end = offsets[node + 1];
  int deg = end - start;
  const float* hrow = h + (size_t)node * HID;
  float hv0 = hrow[lane], hv1 = hrow[lane + 64];
  float a0 = 0.f, a1 = 0.f;

  int batch = min(deg, 64);
  int myc = (lane < batch) ? csr_col[start + lane] : 0;
  int j = 0;
  for (; j + 8 <= batch; j += 8) {
    const float* p0 = h + (size_t)__shfl(myc, j + 0) * HID;
    const float* p1 = h + (size_t)__shfl(myc, j + 1) * HID;
    const float* p2 = h + (size_t)__shfl(myc, j + 2) * HID;
    const float* p3 = h + (size_t)__shfl(myc, j + 3) * HID;
    const float* p4 = h + (size_t)__shfl(myc, j + 4) * HID;
    const float* p5 = h + (size_t)__shfl(myc, j + 5) * HID;
    const float* p6 = h + (size_t)__shfl(myc, j + 6) * HID;
    const float* p7 = h + (size_t)__shfl(myc, j + 7) * HID;
    float x00 = p0[lane], x01 = p0[lane + 64];
    float x10 = p1[lane], x11 = p1[lane + 64];
    float x20 = p2[lane], x21 = p2[lane + 64];
    float x30 = p3[lane], x31 = p3[lane + 64];
    float x40 = p4[lane], x41 = p4[lane + 64];
    float x50 = p5[lane], x51 = p5[lane + 64];
    float x60 = p6[lane], x61 = p6[lane + 64];
    float x70 = p7[lane], x71 = p7[lane + 64];
    a0 += fabsf(hv0 - x00) + fabsf(hv0 - x10) + fabsf(hv0 - x20) + fabsf(hv0 - x30)
        + fabsf(hv0 - x40) + fabsf(hv0 - x50) + fabsf(hv0 - x60) + fabsf(hv0 - x70);
    a1 += fabsf(hv1 - x01) + fabsf(hv1 - x11) + fabsf(hv1 - x21) + fabsf(hv1 - x31)
        + fabsf(hv1 - x41) + fabsf(hv1 - x51) + fabsf(hv1 - x61) + fabsf(hv1 - x71);
  }
  for (; j < batch; ++j) {
    const float* p = h + (size_t)__shfl(myc, j) * HID;
    a0 += fabsf(hv0 - p[lane]);
    a1 += fabsf(hv1 - p[lane + 64]);
  }
  for (int e = start + 64; e < end; ++e) {
    int c = csr_col[e];
    const float* p = h + (size_t)c * HID;
    a0 += fabsf(hv0 - p[lane]);
    a1 += fabsf(hv1 - p[lane + 64]);
  }
  diff[(size_t)node * HID + lane] = a0;
  diff[(size_t)node * HID + lane + 64] = a1;
}

// ---------------- tiled fp32 GEMM: C = relu([A1|A2] @ BT + bias), opt tau ----
// 512 threads/block, 8x4 acc/thread. Round-7 profile showed the 256-thread
// version was GRID-limited: 782 blocks x 4 waves = 12 waves/CU (19% occ) while
// LDS/VGPR allowed 24+. Same tile, same per-element fmaf order (h bit-identical),
// twice the waves/CU. (Register-prefetch variant regressed: VGPR 148, occ 8.6%.)
template<bool TAU>
__global__ __launch_bounds__(512)
void gemm_kernel(const float* __restrict__ A1, const float* __restrict__ A2,
                 const float* __restrict__ BT, const float* __restrict__ bias,
                 float* __restrict__ C, int M, int nchunks,
                 const float* __restrict__ Wt, const float* __restrict__ bt,
                 float* __restrict__ tau_out) {
  __shared__ float As[32][132];   // [k][i], padded leading dim
  __shared__ float Bs[32][128];   // [k][c]
  __shared__ float taured[128];
  int tid = threadIdx.x;
  int tx = tid & 31;   // col group: cols tx + 32*u, u<4
  int ty = tid >> 5;   // row group: rows ty*8 + r, r<8 (ty in 0..15)
  int i0 = blockIdx.x * 128;
  float acc[8][4] = {};

  for (int kc = 0; kc < nchunks; ++kc) {
    const float* A = (kc < 4) ? A1 : A2;
    int ksrc = (kc & 3) * 32;
    int kglob = kc * 32;
    #pragma unroll
    for (int q = 0; q < 2; ++q) {     // stage A (transposed into LDS)
      int f = q * 512 + tid;
      int i = f >> 3;
      int kq = (f & 7) << 2;
      int ig = i0 + i; if (ig >= M) ig = M - 1;
      float4 v = *(const float4*)(A + (size_t)ig * HID + ksrc + kq);
      As[kq + 0][i] = v.x; As[kq + 1][i] = v.y;
      As[kq + 2][i] = v.z; As[kq + 3][i] = v.w;
    }
    #pragma unroll
    for (int q = 0; q < 2; ++q) {     // stage B
      int f = q * 512 + tid;
      int k = f >> 5; int c4 = (f & 31) << 2;
      *(float4*)&Bs[k][c4] = *(const float4*)(BT + (size_t)(kglob + k) * HID + c4);
    }
    __syncthreads();
    #pragma unroll
    for (int k = 0; k < 32; ++k) {
      float a[8], b[4];
      const float4* ap = (const float4*)&As[k][ty * 8];
      float4 a0 = ap[0], a1 = ap[1];
      a[0]=a0.x; a[1]=a0.y; a[2]=a0.z; a[3]=a0.w;
      a[4]=a1.x; a[5]=a1.y; a[6]=a1.z; a[7]=a1.w;
      #pragma unroll
      for (int u = 0; u < 4; ++u) b[u] = Bs[k][tx + 32 * u];
      #pragma unroll
      for (int r = 0; r < 8; ++r)
        #pragma unroll
        for (int u = 0; u < 4; ++u)
          acc[r][u] = fmaf(a[r], b[u], acc[r][u]);
    }
    __syncthreads();
  }

  float bias_r[4], wt_r[4];
  #pragma unroll
  for (int u = 0; u < 4; ++u) { bias_r[u] = bias[tx + 32 * u]; wt_r[u] = 0.f; }
  if constexpr (TAU) {
    #pragma unroll
    for (int u = 0; u < 4; ++u) wt_r[u] = Wt[tx + 32 * u];
  }
  #pragma unroll
  for (int r = 0; r < 8; ++r) {
    int row = i0 + ty * 8 + r;
    bool ok = row < M;
    float p = 0.f;
    #pragma unroll
    for (int u = 0; u < 4; ++u) {
      float v = fmaxf(acc[r][u] + bias_r[u], 0.f);
      if (ok) C[(size_t)row * HID + tx + 32 * u] = v;
      p = fmaf(v, wt_r[u], p);
    }
    if constexpr (TAU) {
      p += __shfl_down(p, 16, 32);
      p += __shfl_down(p, 8, 32);
      p += __shfl_down(p, 4, 32);
      p += __shfl_down(p, 2, 32);
      p += __shfl_down(p, 1, 32);
      if (tx == 0) taured[ty * 8 + r] = p;
    }
  }
  if constexpr (TAU) {
    __syncthreads();
    if (tid < 128) {
      int row = i0 + tid;
      if (row < M) {
        float pre = taured[tid] + bt[0];
        float tau = (pre > 20.f) ? pre : log1pf(expf(pre));
        tau_out[row] = tau;
      }
    }
  }
}

// ---------------- mask + compaction ----------------
// np semantics: floor(1/tau).astype(int32) overflows to INT_MIN for 1/tau >= 2^31
// -> n_updates <= 0 -> NOT masked even though tau < 0.005.
__global__ void compact_kernel(const float* __restrict__ tau, int* __restrict__ list,
                               int* __restrict__ count, int N) {
  for (int i = blockIdx.x * blockDim.x + threadIdx.x; i < N; i += gridDim.x * blockDim.x) {
    float t = tau[i];
    if (t < 0.005f && (1.0f / t) < 2147483648.0f) {
      int p = atomicAdd(count, 1);
      list[p] = i;
    }
  }
}

// ---------------- masked GRU, 16 nodes / block ----------------
__global__ __launch_bounds__(256)
void gru_kernel(const float* __restrict__ diff, float* __restrict__ h,
                const int* __restrict__ list, const int* __restrict__ count,
                const float* __restrict__ WihT, const float* __restrict__ WhhT,
                const float* __restrict__ b_ih, const float* __restrict__ b_hh) {
  int cnt = *count;
  int base = blockIdx.x * 16;
  if (base >= cnt) return;
  __shared__ float dl[16][HID];
  __shared__ float hl[16][HID];
  __shared__ int ids[16];
  int tid = threadIdx.x;
  if (tid < 16) ids[tid] = (base + tid < cnt) ? list[base + tid] : -1;
  __syncthreads();
  #pragma unroll
  for (int q = 0; q < 8; ++q) {
    int f = q * 256 + tid;
    int r = f >> 7, c = f & 127;
    int id = ids[r];
    int src = (id >= 0) ? id : 0;
    dl[r][c] = diff[(size_t)src * HID + c];
    hl[r][c] = h[(size_t)src * HID + c];
  }
  __syncthreads();
  int tx = tid & 127, ty = tid >> 7;
  float air[8] = {}, aiz[8] = {}, ain[8] = {}, ahr[8] = {}, ahz[8] = {}, ahn[8] = {};
  for (int k = 0; k < HID; ++k) {
    float wir = WihT[k * 384 + tx];
    float wiz = WihT[k * 384 + 128 + tx];
    float win = WihT[k * 384 + 256 + tx];
    float whr = WhhT[k * 384 + tx];
    float whz = WhhT[k * 384 + 128 + tx];
    float whn = WhhT[k * 384 + 256 + tx];
    #pragma unroll
    for (int r = 0; r < 8; ++r) {
      float dk = dl[ty * 8 + r][k];
      float hk = hl[ty * 8 + r][k];
      air[r] = fmaf(dk, wir, air[r]);
      aiz[r] = fmaf(dk, wiz, aiz[r]);
      ain[r] = fmaf(dk, win, ain[r]);
      ahr[r] = fmaf(hk, whr, ahr[r]);
      ahz[r] = fmaf(hk, whz, ahz[r]);
      ahn[r] = fmaf(hk, whn, ahn[r]);
    }
  }
  float bir = b_ih[tx], biz = b_ih[128 + tx], bin = b_ih[256 + tx];
  float bhr = b_hh[tx], bhz = b_hh[128 + tx], bhn = b_hh[256 + tx];
  #pragma unroll
  for (int r = 0; r < 8; ++r) {
    int id = ids[ty * 8 + r];
    if (id < 0) continue;
    float rg = 1.f / (1.f + expf(-((air[r] + bir) + (ahr[r] + bhr))));
    float z  = 1.f / (1.f + expf(-((aiz[r] + biz) + (ahz[r] + bhz))));
    float n  = tanhf((ain[r] + bin) + rg * (ahn[r] + bhn));
    float hv = hl[ty * 8 + r][tx];
    h[(size_t)id * HID + tx] = (1.f - z) * n + z * hv;
  }
}

// ---------------- output head: out = h @ Wo^T + bo  (wave per node) ----------
__global__ void out_kernel(const float* __restrict__ h, const float* __restrict__ Wo,
                           const float* __restrict__ bo, float* __restrict__ out, int N) {
  int g = blockIdx.x * blockDim.x + threadIdx.x;
  int node = g >> 6;
  int lane = threadIdx.x & 63;
  if (node >= N) return;
  float h0 = h[(size_t)node * HID + lane];
  float h1 = h[(size_t)node * HID + 64 + lane];
  float s0 = h0 * Wo[lane] + h1 * Wo[64 + lane];
  float s1 = h0 * Wo[128 + lane] + h1 * Wo[192 + lane];
  for (int d = 32; d; d >>= 1) {
    s0 += __shfl_down(s0, d);
    s1 += __shfl_down(s1, d);
  }
  if (lane == 0) {
    out[(size_t)node * 2 + 0] = s0 + bo[0];
    out[(size_t)node * 2 + 1] = s1 + bo[1];
  }
}

extern "C" void kernel_launch(void* const* d_in, const int* in_sizes, int n_in,
                              void* d_out, int out_size, void* d_ws, size_t ws_size,
                              hipStream_t stream) {
  const float* x    = (const float*)d_in[0];
  const int*   ei   = (const int*)d_in[1];
  const float* W_in = (const float*)d_in[2];
  const float* b_in = (const float*)d_in[3];
  const float* Wd   = (const float*)d_in[4];
  const float* bd   = (const float*)d_in[5];
  const float* Wt   = (const float*)d_in[6];
  const float* bt   = (const float*)d_in[7];
  const float* W_ih = (const float*)d_in[8];
  const float* W_hh = (const float*)d_in[9];
  const float* b_ih = (const float*)d_in[10];
  const float* b_hh = (const float*)d_in[11];
  const float* Wo   = (const float*)d_in[12];
  const float* bo   = (const float*)d_in[13];

  const int N = in_sizes[0] / HID;      // 100000
  const int E = in_sizes[1] / 2;        // 1600000
  const int* rowp = ei;
  const int* colp = ei + E;
  const int nbuck = (N + (1 << BSHIFT) - 1) >> BSHIFT;   // 782 (<=1024)

  // workspace carve-up (256B aligned)
  char* p = (char*)d_ws;
  auto alloc = [&](size_t bytes) { void* r = (void*)p; p += (bytes + 255) & ~(size_t)255; return r; };
  float* hA     = (float*)alloc((size_t)N * HID * 4);
  float* hB     = (float*)alloc((size_t)N * HID * 4);
  float* diff   = (float*)alloc((size_t)N * HID * 4);
  float* WinT   = (float*)alloc(128 * 128 * 4);
  float* WdT0   = (float*)alloc(256 * 128 * 4);
  float* WdT1   = (float*)alloc(256 * 128 * 4);
  float* WihT   = (float*)alloc(128 * 384 * 4);
  float* WhhT   = (float*)alloc(128 * 384 * 4);
  float* tau0   = (float*)alloc((size_t)N * 4);
  int*   list   = (int*)alloc((size_t)N * 4);
  int*   count  = (int*)alloc(256);
  int*   countsT= (int*)alloc((size_t)1024 * NSB * 4);
  int*   btotal = (int*)alloc(1024 * 4);
  int*   bstart = (int*)alloc(1028 * 4);
  int*   offs   = (int*)alloc(((size_t)N + 1) * 4);
  int*   csrcol = (int*)alloc((size_t)E * 4);
  int2*  ebuf   = (int2*)alloc((size_t)E * 8);

  float* out_ptr = (float*)d_out;            // [N,2] flat
  float* tau_out = (float*)d_out + (size_t)N * 2;  // [N]

  // weight transposes
  transpose_kernel<<<(128 * 128 + 255) / 256, 256, 0, stream>>>(W_in, WinT, 128, 128);
  transpose_kernel<<<(128 * 256 + 255) / 256, 256, 0, stream>>>(Wd, WdT0, 128, 256);
  transpose_kernel<<<(128 * 256 + 255) / 256, 256, 0, stream>>>(Wd + 128 * 256, WdT1, 128, 256);
  transpose_kernel<<<(384 * 128 + 255) / 256, 256, 0, stream>>>(W_ih, WihT, 384, 128);
  transpose_kernel<<<(384 * 128 + 255) / 256, 256, 0, stream>>>(W_hh, WhhT, 384, 128);

  // CSR build, no global atomics (reused by both layers)
  ecount_kernel<<<NSB, 256, 0, stream>>>(rowp, countsT, E, nbuck);
  bprefix_kernel<<<nbuck, NSB, 0, stream>>>(countsT, btotal, nbuck);
  bstart_kernel<<<1, 1024, 0, stream>>>(btotal, bstart, offs, N, nbuck);
  escatter_kernel<<<NSB, 256, 0, stream>>>(rowp, colp, countsT, bstart, ebuf, E, nbuck);
  bsort_kernel<<<nbuck, 256, 0, stream>>>(ebuf, bstart, offs, csrcol, N, nbuck);

  const int gemm_blocks = (N + 127) / 128;
  const int agg_blocks = (N + 3) / 4;

  // input layer: hA = relu(x @ Win^T + b_in)
  gemm_kernel<false><<<gemm_blocks, 512, 0, stream>>>(
      x, nullptr, WinT, b_in, hA, N, 4, nullptr, nullptr, nullptr);

  // ---- layer 0 ----
  aggregate_kernel<<<agg_blocks, 256, 0, stream>>>(hA, offs, csrcol, diff, N);
  gemm_kernel<true><<<gemm_blocks, 512, 0, stream>>>(
      hA, diff, WdT0, bd, hB, N, 8, Wt, bt, tau0);
  hipMemsetAsync(count, 0, 4, stream);
  compact_kernel<<<(N + 255) / 256, 256, 0, stream>>>(tau0, list, count, N);
  gru_kernel<<<(N + 15) / 16, 256, 0, stream>>>(diff, hB, list, count, WihT, WhhT, b_ih, b_hh);

  // ---- layer 1 ----
  aggregate_kernel<<<agg_blocks, 256, 0, stream>>>(hB, offs, csrcol, diff, N);
  gemm_kernel<true><<<gemm_blocks, 512, 0, stream>>>(
      hB, diff, WdT1, bd + 128, hA, N, 8, Wt, bt, tau_out);
  hipMemsetAsync(count, 0, 4, stream);
  compact_kernel<<<(N + 255) / 256, 256, 0, stream>>>(tau_out, list, count, N);
  gru_kernel<<<(N + 15) / 16, 256, 0, stream>>>(diff, hA, list, count, WihT, WhhT, b_ih, b_hh);

  // output head
  out_kernel<<<((size_t)N * 64 + 255) / 256, 256, 0, stream>>>(hA, Wo, bo, out_ptr, N);
}